// Round 7
// baseline (6758.043 us; speedup 1.0000x reference)
//
#include <hip/hip_runtime.h>
#include <math.h>

#define CC 20
#define BB 256
#define HH 10
#define SS 64
#define AA 16
#define HD 128
#define RH 64
#define CBR (CC*BB)      // 5120 rows
#define NSNN 15

// Replicate npy_logaddexpf(u, 0.f): float32 chain, expf/log1pf at
// correctly-rounded level via f64 internals. (Verified bit-exact rounds 4-6.)
__device__ __forceinline__ float softplus_np(float u) {
    if (u > 0.0f) {
        float ef = (float)exp((double)(-u));
        float l1 = (float)log1p((double)ef);
        return __fadd_rn(u, l1);
    } else if (u < 0.0f) {
        float ef = (float)exp((double)u);
        return (float)log1p((double)ef);
    } else {
        return 0.69314718055994530942f;
    }
}

// One block = one rollout row (cb = c*B + b), full 10-step rollout + reward
// fused. 128 threads, thread j = hidden unit j. All dots are single
// sequential-k fmaf chains; elementwise ops separately rounded — bit-exact
// vs the np-f32 reference (verified rounds 4-6).
//
// Scheduling notes (hard-won over rounds 5-6):
//  - NO launch_bounds min-waves arg: round 5 (unbounded, chunked loop) hit
//    196 VGPR -> 12% occupancy; round 6 (forced 64 VGPR) spilled cur2[] to
//    scratch -> 2.8 GB HBM traffic. This version keeps the hot-loop live set
//    ~30 VGPRs by using a simple rolled k-loop with no prefetch machinery.
//  - spike masks cached in 2 VGPRs/lane; per-k wave-uniform mask via
//    readlane -> SGPR; sv = ((m>>t)&1)*1.0f is SALU work co-issued with the
//    VALU fmaf. m==0 rows are skipped by a scalar branch (~half of them).
__global__ __launch_bounds__(128) void rollout_kernel(
    const float* __restrict__ current_state,   // [B,S]
    const float* __restrict__ actions,         // [C,B,H,A]
    const float* __restrict__ noise,           // [C,B,H,S]
    const float* __restrict__ Wse, const float* __restrict__ bse,
    const float* __restrict__ Wae, const float* __restrict__ bae,
    const float* __restrict__ W1,  const float* __restrict__ b1,
    const float* __restrict__ W2,  const float* __restrict__ b2,
    const float* __restrict__ Wdec, const float* __restrict__ bdec,
    const float* __restrict__ Wunc, const float* __restrict__ bunc,
    const float* __restrict__ Wr1, const float* __restrict__ br1,
    const float* __restrict__ Wr2, const float* __restrict__ br2,
    const float* __restrict__ Wr3, const float* __restrict__ br3,
    float* __restrict__ cum)                   // [CB]
{
    const int cb = blockIdx.x;
    const int j  = threadIdx.x;

    __shared__ float    s_state[SS];
    __shared__ float    s_sae[2*HD];
    __shared__ unsigned s_mask[HD];
    __shared__ float    s_mem2[HD];
    __shared__ float    s_mu[2*SS];      // [0..63]=mean, [64..127]=u
    __shared__ float    s_x[SS + AA];
    __shared__ float    s_h[RH];
    __shared__ float    s_h2[RH];

    if (j < SS) s_state[j] = current_state[(size_t)(cb % BB)*SS + j];

    float total = 0.0f;                  // thread 0 only

    for (int h = 0; h < HH; h++) {
        __syncthreads();                 // s_state (and prior-iter LDS) ready

        // ---- se = relu(state @ Wse + bse): sequential-k single chain
        float acc = 0.0f;
        for (int i = 0; i < SS; i++)
            acc = fmaf(s_state[i], Wse[i*HD + j], acc);
        float se = fmaxf(__fadd_rn(acc, bse[j]), 0.0f);

        // ---- ae = relu(act @ Wae + bae)
        const float* act = actions + ((size_t)cb*HH + h)*AA;
        acc = 0.0f;
        for (int i = 0; i < AA; i++)
            acc = fmaf(act[i], Wae[i*HD + j], acc);
        float ae = fmaxf(__fadd_rn(acc, bae[j]), 0.0f);

        s_sae[j]      = se;
        s_sae[HD + j] = ae;
        __syncthreads();

        // ---- cur = concat(se, ae) @ W1 + b1 (constant across SNN steps)
        acc = 0.0f;
        for (int i = 0; i < 2*HD; i++)
            acc = fmaf(s_sae[i], W1[i*HD + j], acc);
        const float cur = __fadd_rn(acc, b1[j]);

        // ---- mem1 recurrence -> 15-bit spike mask (exact op order)
        unsigned mask = 0u;
        float m1 = 0.0f;
        #pragma unroll
        for (int t = 0; t < NSNN; t++) {
            float sp1old = (__fsub_rn(m1, 1.0f) > 0.0f) ? 1.0f : 0.0f;
            m1 = __fsub_rn(__fadd_rn(__fmul_rn(0.9f, m1), cur), sp1old);
            if (__fsub_rn(m1, 1.0f) > 0.0f) mask |= (1u << t);
        }
        s_mask[j] = mask;
        __syncthreads();

        // ---- cache all 128 masks in 2 VGPRs per lane (one LDS round-trip;
        // both waves load the same values since lane = j & 63)
        const int lane = j & 63;
        unsigned mlo = s_mask[lane];
        unsigned mhi = s_mask[64 + lane];

        // ---- cur2[t] = spk[t] @ W2, one k-ascending pass, all t at once.
        // fmaf(sv in {0,1}, w, acc) with sv=0 is an exact identity, so each
        // cur2[t] equals the reference's sequential chain bit-for-bit; the
        // m==0 skip removes only exact-zero terms.
        float cur2[NSNN];
        #pragma unroll
        for (int t = 0; t < NSNN; t++) cur2[t] = 0.0f;

        const float* W2j = W2 + j;
        for (int k = 0; k < 64; k++) {
            float w = W2j[(size_t)k * HD];
            unsigned m = (unsigned)__builtin_amdgcn_readlane((int)mlo, k);
            if (m == 0u) continue;       // wave-uniform scalar branch
            #pragma unroll
            for (int t = 0; t < NSNN; t++) {
                float sv = __uint_as_float(((m >> t) & 1u) * 0x3f800000u);
                cur2[t] = fmaf(sv, w, cur2[t]);
            }
        }
        for (int k = 0; k < 64; k++) {
            float w = W2j[(size_t)(64 + k) * HD];
            unsigned m = (unsigned)__builtin_amdgcn_readlane((int)mhi, k);
            if (m == 0u) continue;
            #pragma unroll
            for (int t = 0; t < NSNN; t++) {
                float sv = __uint_as_float(((m >> t) & 1u) * 0x3f800000u);
                cur2[t] = fmaf(sv, w, cur2[t]);
            }
        }

        // ---- mem2 recurrence (exact op order)
        const float b2j = b2[j];
        float m2 = 0.0f;
        #pragma unroll
        for (int t = 0; t < NSNN; t++) {
            float c2 = __fadd_rn(cur2[t], b2j);
            float sp2old = (__fsub_rn(m2, 1.0f) > 0.0f) ? 1.0f : 0.0f;
            m2 = __fsub_rn(__fadd_rn(__fmul_rn(0.9f, m2), c2), sp2old);
        }
        s_mem2[j] = m2;
        __syncthreads();

        // ---- decode, wave-split: threads 0..63 mean, 64..127 unc
        {
            const float* W    = (j < SS) ? Wdec : Wunc;
            const float* bias = (j < SS) ? bdec : bunc;
            int o = j & (SS - 1);
            float c = 0.0f;
            for (int n = 0; n < HD; n++)
                c = fmaf(s_mem2[n], W[n*SS + o], c);
            s_mu[j] = __fadd_rn(c, bias[o]);
        }
        __syncthreads();

        // ---- sample next state; feed both next world step and reward
        if (j < SS) {
            float mean = s_mu[j];
            float u    = s_mu[SS + j];
            float var  = softplus_np(u);
            float sv   = sqrtf(__fadd_rn(var, 1e-8f));
            float nz   = noise[((size_t)cb*HH + h)*SS + j];
            float ns   = __fadd_rn(mean, __fmul_rn(nz, sv));
            s_x[j]     = ns;
            s_state[j] = ns;
        }
        if (j < AA) s_x[SS + j] = act[j];
        __syncthreads();

        // ---- reward: relu(x@Wr1+br1) -> relu(@Wr2+br2) -> @Wr3+br3
        if (j < RH) {
            float a = 0.0f;
            for (int i = 0; i < SS + AA; i++)
                a = fmaf(s_x[i], Wr1[i*RH + j], a);
            s_h[j] = fmaxf(__fadd_rn(a, br1[j]), 0.0f);
        }
        __syncthreads();
        if (j < RH) {
            float g = 0.0f;
            for (int i = 0; i < RH; i++)
                g = fmaf(s_h[i], Wr2[i*RH + j], g);
            s_h2[j] = fmaxf(__fadd_rn(g, br2[j]), 0.0f);
        }
        __syncthreads();
        if (j == 0) {
            float r = 0.0f;
            for (int k = 0; k < RH; k++)
                r = fmaf(s_h2[k], Wr3[k], r);
            r = __fadd_rn(r, br3[0]);
            total = __fadd_rn(total, r);           // sequential sum over h
        }
    }
    if (j == 0) cum[cb] = total;
}

// One block per batch element b: f32 argmax over C (strict > = first max),
// gather best action. (Bit-exact, unchanged.)
__global__ __launch_bounds__(64) void select_kernel(
    const float* __restrict__ cum,      // [CB], cb = c*B + b
    const float* __restrict__ actions,  // [C,B,H,A]
    float* __restrict__ out)            // [B*H*A] actions then [B] values
{
    const int b = blockIdx.x;
    const int j = threadIdx.x;
    __shared__ int s_c;

    if (j == 0) {
        float best = cum[b];            // c = 0
        int bc = 0;
        for (int c = 1; c < CC; c++) {
            float v = cum[(size_t)c*BB + b];
            if (v > best) { best = v; bc = c; }
        }
        s_c = bc;
        out[(size_t)BB*HH*AA + b] = best;
    }
    __syncthreads();
    const int bc = s_c;
    const float* src = actions + ((size_t)bc*BB + b)*HH*AA;
    for (int i = j; i < HH*AA; i += 64) out[(size_t)b*HH*AA + i] = src[i];
}

extern "C" void kernel_launch(void* const* d_in, const int* in_sizes, int n_in,
                              void* d_out, int out_size, void* d_ws, size_t ws_size,
                              hipStream_t stream)
{
    const float* current_state = (const float*)d_in[0];
    const float* actions = (const float*)d_in[1];
    const float* noise   = (const float*)d_in[2];
    const float* Wse = (const float*)d_in[3];
    const float* bse = (const float*)d_in[4];
    const float* Wae = (const float*)d_in[5];
    const float* bae = (const float*)d_in[6];
    const float* W1  = (const float*)d_in[7];
    const float* b1  = (const float*)d_in[8];
    const float* W2  = (const float*)d_in[9];
    const float* b2  = (const float*)d_in[10];
    const float* Wdec = (const float*)d_in[11];
    const float* bdec = (const float*)d_in[12];
    const float* Wunc = (const float*)d_in[13];
    const float* bunc = (const float*)d_in[14];
    const float* Wr1 = (const float*)d_in[15];
    const float* br1 = (const float*)d_in[16];
    const float* Wr2 = (const float*)d_in[17];
    const float* br2 = (const float*)d_in[18];
    const float* Wr3 = (const float*)d_in[19];
    const float* br3 = (const float*)d_in[20];

    float* cum = (float*)d_ws;                          // 5120 f32

    rollout_kernel<<<CBR, HD, 0, stream>>>(current_state, actions, noise,
        Wse, bse, Wae, bae, W1, b1, W2, b2, Wdec, bdec, Wunc, bunc,
        Wr1, br1, Wr2, br2, Wr3, br3, cum);
    select_kernel<<<BB, 64, 0, stream>>>(cum, actions, (float*)d_out);
}

// Round 8
// 848.093 us; speedup vs baseline: 7.9685x; 7.9685x over previous
//
#include <hip/hip_runtime.h>
#include <math.h>

#define CC 20
#define BB 256
#define HH 10
#define SS 64
#define AA 16
#define HD 128
#define RH 64
#define CBR (CC*BB)      // 5120 rows
#define NSNN 15

// Replicate npy_logaddexpf(u, 0.f): float32 chain, expf/log1pf at
// correctly-rounded level via f64 internals. (Verified bit-exact rounds 4-7.)
__device__ __forceinline__ float softplus_np(float u) {
    if (u > 0.0f) {
        float ef = (float)exp((double)(-u));
        float l1 = (float)log1p((double)ef);
        return __fadd_rn(u, l1);
    } else if (u < 0.0f) {
        float ef = (float)exp((double)u);
        return (float)log1p((double)ef);
    } else {
        return 0.69314718055994530942f;
    }
}

// One block = one rollout row (cb), ONE horizon step h (round-4 structure:
// separate per-h launches keep the allocator lean — 32 VGPR there vs 196-212
// for every fused-h variant, where cross-phase software pipelining exploded
// the live set). 128 threads, thread j = hidden unit j.
//
// All dots are single sequential-k fmaf chains; elementwise ops separately
// rounded (__f*_rn) — bit-exact vs the np-f32 reference (verified rounds 4-7).
//
// SNN inner product (bit-exact, verified rounds 5-7): mem1 depends only on
// cur, so compute the 15-bit spike mask per unit first, then accumulate all
// 15 cur2[t] in ONE k-ascending pass with 15-way ILP. fmaf(sv in {0,1}, w,
// acc) with sv=0 is an exact identity (acc stays +0 under skips), so each
// cur2[t] equals the reference's sequential chain bit-for-bit. Masks ride in
// 2 VGPRs/lane; per-k wave-uniform mask via readlane (SALU control path);
// m==0 units skipped by scalar branch. k-loops pinned rolled (#pragma
// unroll 1) to block the round-5/7 register blowup; t-loops fully unrolled
// so cur2[] stays in registers (runtime-indexed arrays would hit scratch).
__global__ __launch_bounds__(128) void world_kernel(
    int h,
    const float* __restrict__ current_state,   // [B,S]
    const float* __restrict__ actions,         // [C,B,H,A]
    const float* __restrict__ noise,           // [C,B,H,S]
    const float* __restrict__ Wse, const float* __restrict__ bse,
    const float* __restrict__ Wae, const float* __restrict__ bae,
    const float* __restrict__ W1,  const float* __restrict__ b1,
    const float* __restrict__ W2,  const float* __restrict__ b2,
    const float* __restrict__ Wdec, const float* __restrict__ bdec,
    const float* __restrict__ Wunc, const float* __restrict__ bunc,
    float* __restrict__ states)                // [H, CB, S]
{
    const int cb = blockIdx.x;
    const int j  = threadIdx.x;

    __shared__ float    s_state[SS];
    __shared__ float    s_sae[2*HD];
    __shared__ unsigned s_mask[HD];
    __shared__ float    s_mem2[HD];
    __shared__ float    s_mu[2*SS];      // [0..63]=mean, [64..127]=u

    if (j < SS) {
        s_state[j] = (h == 0) ? current_state[(size_t)(cb % BB)*SS + j]
                              : states[((size_t)(h-1)*CBR + cb)*SS + j];
    }
    __syncthreads();

    // ---- se = relu(state @ Wse + bse): sequential-k single chain
    float acc = 0.0f;
    for (int i = 0; i < SS; i++)
        acc = fmaf(s_state[i], Wse[i*HD + j], acc);
    float se = fmaxf(__fadd_rn(acc, bse[j]), 0.0f);

    // ---- ae = relu(act @ Wae + bae)
    const float* act = actions + ((size_t)cb*HH + h)*AA;
    acc = 0.0f;
    for (int i = 0; i < AA; i++)
        acc = fmaf(act[i], Wae[i*HD + j], acc);
    float ae = fmaxf(__fadd_rn(acc, bae[j]), 0.0f);

    s_sae[j]      = se;
    s_sae[HD + j] = ae;
    __syncthreads();

    // ---- cur = concat(se, ae) @ W1 + b1 (constant across SNN steps)
    acc = 0.0f;
    for (int i = 0; i < 2*HD; i++)
        acc = fmaf(s_sae[i], W1[i*HD + j], acc);
    const float cur = __fadd_rn(acc, b1[j]);

    // ---- mem1 recurrence -> 15-bit spike mask (exact op order)
    unsigned mask = 0u;
    float m1 = 0.0f;
    #pragma unroll
    for (int t = 0; t < NSNN; t++) {
        float sp1old = (__fsub_rn(m1, 1.0f) > 0.0f) ? 1.0f : 0.0f;
        m1 = __fsub_rn(__fadd_rn(__fmul_rn(0.9f, m1), cur), sp1old);
        if (__fsub_rn(m1, 1.0f) > 0.0f) mask |= (1u << t);
    }
    s_mask[j] = mask;
    __syncthreads();

    // ---- cache all 128 masks in 2 VGPRs per lane (lane = j & 63, so both
    // waves hold identical copies)
    const int lane = j & 63;
    unsigned mlo = s_mask[lane];
    unsigned mhi = s_mask[64 + lane];

    // ---- cur2[t] = spk[t] @ W2, one k-ascending pass, all 15 t at once
    float cur2[NSNN];
    #pragma unroll
    for (int t = 0; t < NSNN; t++) cur2[t] = 0.0f;

    const float* W2j = W2 + j;
    #pragma unroll 1
    for (int k = 0; k < 64; k++) {
        float w = W2j[(size_t)k * HD];
        unsigned m = (unsigned)__builtin_amdgcn_readlane((int)mlo, k);
        if (m == 0u) continue;           // wave-uniform scalar branch
        #pragma unroll
        for (int t = 0; t < NSNN; t++) {
            float sv = __uint_as_float(((m >> t) & 1u) * 0x3f800000u);
            cur2[t] = fmaf(sv, w, cur2[t]);
        }
    }
    #pragma unroll 1
    for (int k = 0; k < 64; k++) {
        float w = W2j[(size_t)(64 + k) * HD];
        unsigned m = (unsigned)__builtin_amdgcn_readlane((int)mhi, k);
        if (m == 0u) continue;
        #pragma unroll
        for (int t = 0; t < NSNN; t++) {
            float sv = __uint_as_float(((m >> t) & 1u) * 0x3f800000u);
            cur2[t] = fmaf(sv, w, cur2[t]);
        }
    }

    // ---- mem2 recurrence (exact op order)
    const float b2j = b2[j];
    float m2 = 0.0f;
    #pragma unroll
    for (int t = 0; t < NSNN; t++) {
        float c2 = __fadd_rn(cur2[t], b2j);
        float sp2old = (__fsub_rn(m2, 1.0f) > 0.0f) ? 1.0f : 0.0f;
        m2 = __fsub_rn(__fadd_rn(__fmul_rn(0.9f, m2), c2), sp2old);
    }
    s_mem2[j] = m2;
    __syncthreads();

    // ---- decode, wave-split: threads 0..63 mean, 64..127 unc
    {
        const float* W    = (j < SS) ? Wdec : Wunc;
        const float* bias = (j < SS) ? bdec : bunc;
        int o = j & (SS - 1);
        float c = 0.0f;
        for (int n = 0; n < HD; n++)
            c = fmaf(s_mem2[n], W[n*SS + o], c);
        s_mu[j] = __fadd_rn(c, bias[o]);
    }
    __syncthreads();

    // ---- sample next state
    if (j < SS) {
        float mean = s_mu[j];
        float u    = s_mu[SS + j];
        float var  = softplus_np(u);
        float sv   = sqrtf(__fadd_rn(var, 1e-8f));
        float nz   = noise[((size_t)cb*HH + h)*SS + j];
        states[((size_t)h*CBR + cb)*SS + j] = __fadd_rn(mean, __fmul_rn(nz, sv));
    }
}

// One block = one row (cb), 64 threads; loops over H, f32 sequential sum.
// (Round-4 verified bit-exact, unchanged.)
__global__ __launch_bounds__(64) void reward_kernel(
    const float* __restrict__ states,    // [H, CB, S]
    const float* __restrict__ actions,   // [C,B,H,A]
    const float* __restrict__ Wr1, const float* __restrict__ br1,
    const float* __restrict__ Wr2, const float* __restrict__ br2,
    const float* __restrict__ Wr3, const float* __restrict__ br3,
    float* __restrict__ cum)             // [CB]
{
    const int cb = blockIdx.x;
    const int j  = threadIdx.x;
    __shared__ float s_x[SS + AA];
    __shared__ float s_h[RH];
    __shared__ float s_h2[RH];

    float total = 0.0f;
    for (int h = 0; h < HH; h++) {
        __syncthreads();
        s_x[j] = states[((size_t)h*CBR + cb)*SS + j];
        if (j < AA) s_x[SS + j] = actions[((size_t)cb*HH + h)*AA + j];
        __syncthreads();

        float a = 0.0f;
        for (int i = 0; i < SS + AA; i++)
            a = fmaf(s_x[i], Wr1[i*RH + j], a);
        s_h[j] = fmaxf(__fadd_rn(a, br1[j]), 0.0f);
        __syncthreads();

        float g = 0.0f;
        for (int i = 0; i < RH; i++)
            g = fmaf(s_h[i], Wr2[i*RH + j], g);
        s_h2[j] = fmaxf(__fadd_rn(g, br2[j]), 0.0f);
        __syncthreads();

        if (j == 0) {
            float r = 0.0f;
            for (int k = 0; k < RH; k++)
                r = fmaf(s_h2[k], Wr3[k], r);
            r = __fadd_rn(r, br3[0]);
            total = __fadd_rn(total, r);          // sequential sum over h
        }
    }
    if (j == 0) cum[cb] = total;
}

// One block per batch element b: f32 argmax over C (strict > = first max),
// gather best action. (Bit-exact, unchanged.)
__global__ __launch_bounds__(64) void select_kernel(
    const float* __restrict__ cum,      // [CB], cb = c*B + b
    const float* __restrict__ actions,  // [C,B,H,A]
    float* __restrict__ out)            // [B*H*A] actions then [B] values
{
    const int b = blockIdx.x;
    const int j = threadIdx.x;
    __shared__ int s_c;

    if (j == 0) {
        float best = cum[b];            // c = 0
        int bc = 0;
        for (int c = 1; c < CC; c++) {
            float v = cum[(size_t)c*BB + b];
            if (v > best) { best = v; bc = c; }
        }
        s_c = bc;
        out[(size_t)BB*HH*AA + b] = best;
    }
    __syncthreads();
    const int bc = s_c;
    const float* src = actions + ((size_t)bc*BB + b)*HH*AA;
    for (int i = j; i < HH*AA; i += 64) out[(size_t)b*HH*AA + i] = src[i];
}

extern "C" void kernel_launch(void* const* d_in, const int* in_sizes, int n_in,
                              void* d_out, int out_size, void* d_ws, size_t ws_size,
                              hipStream_t stream)
{
    const float* current_state = (const float*)d_in[0];
    const float* actions = (const float*)d_in[1];
    const float* noise   = (const float*)d_in[2];
    const float* Wse = (const float*)d_in[3];
    const float* bse = (const float*)d_in[4];
    const float* Wae = (const float*)d_in[5];
    const float* bae = (const float*)d_in[6];
    const float* W1  = (const float*)d_in[7];
    const float* b1  = (const float*)d_in[8];
    const float* W2  = (const float*)d_in[9];
    const float* b2  = (const float*)d_in[10];
    const float* Wdec = (const float*)d_in[11];
    const float* bdec = (const float*)d_in[12];
    const float* Wunc = (const float*)d_in[13];
    const float* bunc = (const float*)d_in[14];
    const float* Wr1 = (const float*)d_in[15];
    const float* br1 = (const float*)d_in[16];
    const float* Wr2 = (const float*)d_in[17];
    const float* br2 = (const float*)d_in[18];
    const float* Wr3 = (const float*)d_in[19];
    const float* br3 = (const float*)d_in[20];

    float* states = (float*)d_ws;                       // 10*5120*64 f32 = 13.1 MB
    float* cum    = states + (size_t)HH*CBR*SS;         // 5120 f32

    for (int h = 0; h < HH; h++) {
        world_kernel<<<CBR, HD, 0, stream>>>(h, current_state, actions, noise,
            Wse, bse, Wae, bae, W1, b1, W2, b2, Wdec, bdec, Wunc, bunc, states);
    }
    reward_kernel<<<CBR, RH, 0, stream>>>(states, actions, Wr1, br1, Wr2, br2, Wr3, br3, cum);
    select_kernel<<<BB, 64, 0, stream>>>(cum, actions, (float*)d_out);
}